// Round 3
// baseline (657.860 us; speedup 1.0000x reference)
//
#include <hip/hip_runtime.h>
#include <hip/hip_bf16.h>
#include <cstdint>

#define B_   16
#define C_   256
#define N_   8192
#define CN_  128
#define CL_  64
#define MID_ 128

typedef unsigned short u16;
typedef __attribute__((ext_vector_type(8))) short bf8;
typedef __attribute__((ext_vector_type(4))) float f4;

#define MFMA(a, bb, c) __builtin_amdgcn_mfma_f32_16x16x32_bf16(a, bb, c, 0, 0, 0)

__device__ inline u16 f2b(float v) {
  uint32_t b = __builtin_bit_cast(uint32_t, v);
  uint32_t r = (b + 0x7FFFu + ((b >> 16) & 1u)) >> 16;
  return (u16)r;
}
__device__ inline float b2f(u16 u) {
  uint32_t b = ((uint32_t)u) << 16;
  return __builtin_bit_cast(float, b);
}
__device__ inline void st4(u16* p, u16 a, u16 b, u16 c, u16 d) {
  unsigned long long v = (unsigned long long)a | ((unsigned long long)b << 16) |
                         ((unsigned long long)c << 32) | ((unsigned long long)d << 48);
  *(unsigned long long*)p = v;
}

// ---------------------------------------------------------------------------
// K1: att[b,n,l] = sum_c w_att[c] * curves[b,c,n,l]
// ---------------------------------------------------------------------------
__global__ __launch_bounds__(256) void k_att(const float* __restrict__ curves,
                                             const float* __restrict__ w_att,
                                             float* __restrict__ att) {
  const int blk = blockIdx.x;
  const int b = blk >> 5, nc = blk & 31;
  const int tid = threadIdx.x;
  const float* cb = curves + (size_t)b * C_ * CN_ * CL_ + nc * 256 + tid;
  float a0 = 0.f, a1 = 0.f, a2 = 0.f, a3 = 0.f;
  for (int c0 = 0; c0 < C_; c0 += 4) {
    a0 = fmaf(w_att[c0 + 0], cb[(size_t)(c0 + 0) * 8192], a0);
    a1 = fmaf(w_att[c0 + 1], cb[(size_t)(c0 + 1) * 8192], a1);
    a2 = fmaf(w_att[c0 + 2], cb[(size_t)(c0 + 2) * 8192], a2);
    a3 = fmaf(w_att[c0 + 3], cb[(size_t)(c0 + 3) * 8192], a3);
  }
  att[b * 8192 + nc * 256 + tid] = (a0 + a1) + (a2 + a3);
}

// ---------------------------------------------------------------------------
// K2: dual softmax of att
// ---------------------------------------------------------------------------
__global__ __launch_bounds__(256) void k_softmax(const float* __restrict__ att,
                                                 float* __restrict__ smi,
                                                 float* __restrict__ sma) {
  __shared__ float T[CN_ * CL_];
  __shared__ float rmax[CN_], rrcp[CN_], cmax[CL_], crcp[CL_];
  const int b = blockIdx.x;
  const int tid = threadIdx.x;
  for (int idx = tid; idx < CN_ * CL_; idx += 256) T[idx] = att[b * 8192 + idx];
  __syncthreads();
  if (tid < 128) {
    const int n = tid;
    float mx = -1e30f;
    for (int l = 0; l < CL_; ++l) mx = fmaxf(mx, T[n * 64 + l]);
    float s = 0.f;
    for (int l = 0; l < CL_; ++l) s += __expf(T[n * 64 + l] - mx);
    rmax[n] = mx; rrcp[n] = 1.f / s;
  } else if (tid < 192) {
    const int l = tid - 128;
    float mx = -1e30f;
    for (int n = 0; n < CN_; ++n) mx = fmaxf(mx, T[n * 64 + l]);
    float s = 0.f;
    for (int n = 0; n < CN_; ++n) s += __expf(T[n * 64 + l] - mx);
    cmax[l] = mx; crcp[l] = 1.f / s;
  }
  __syncthreads();
  for (int idx = tid; idx < CN_ * CL_; idx += 256) {
    const int n = idx >> 6, l = idx & 63;
    const float v = T[idx];
    smi[b * 8192 + idx] = __expf(v - rmax[n]) * rrcp[n];
    sma[b * 8192 + idx] = __expf(v - cmax[l]) * crcp[l];
  }
}

// ---------------------------------------------------------------------------
// K3: curve aggregation
// ---------------------------------------------------------------------------
__global__ __launch_bounds__(256) void k_agg(const float* __restrict__ curves,
                                             const float* __restrict__ smi,
                                             const float* __restrict__ sma,
                                             float* __restrict__ cinter,
                                             float* __restrict__ cintra) {
  __shared__ float P[CN_ * CL_];
  const int blk = blockIdx.x;
  const int b = blk >> 8, c = blk & 255;
  const int tid = threadIdx.x;
  const float* src = curves + (size_t)(b * 256 + c) * 8192;
  for (int i4 = tid; i4 < 2048; i4 += 256)
    *(float4*)&P[i4 * 4] = *(const float4*)&src[i4 * 4];
  __syncthreads();
  if (tid < 128) {
    const int n = tid;
    const float* sp = smi + (size_t)(b * 128 + n) * 64;
    float a[4] = {0.f, 0.f, 0.f, 0.f};
    for (int l0 = 0; l0 < 64; l0 += 4) {
      float4 pv = *(const float4*)&P[n * 64 + l0];
      float4 sv = *(const float4*)&sp[l0];
      a[0] = fmaf(pv.x, sv.x, a[0]);
      a[1] = fmaf(pv.y, sv.y, a[1]);
      a[2] = fmaf(pv.z, sv.z, a[2]);
      a[3] = fmaf(pv.w, sv.w, a[3]);
    }
    cinter[(size_t)(b * 256 + c) * 128 + n] = (a[0] + a[1]) + (a[2] + a[3]);
  } else if (tid < 192) {
    const int l = tid - 128;
    float a[4] = {0.f, 0.f, 0.f, 0.f};
    for (int n0 = 0; n0 < 128; n0 += 4) {
      a[0] = fmaf(P[(n0 + 0) * 64 + l], sma[(size_t)(b * 128 + n0 + 0) * 64 + l], a[0]);
      a[1] = fmaf(P[(n0 + 1) * 64 + l], sma[(size_t)(b * 128 + n0 + 1) * 64 + l], a[1]);
      a[2] = fmaf(P[(n0 + 2) * 64 + l], sma[(size_t)(b * 128 + n0 + 2) * 64 + l], a[2]);
      a[3] = fmaf(P[(n0 + 3) * 64 + l], sma[(size_t)(b * 128 + n0 + 3) * 64 + l], a[3]);
    }
    cintra[(size_t)(b * 256 + c) * 64 + l] = (a[0] + a[1]) + (a[2] + a[3]);
  }
}

// ---------------------------------------------------------------------------
// K4: a = wa@cinter ; bm = wb@cintra
// ---------------------------------------------------------------------------
__global__ __launch_bounds__(256) void k_ab(const float* __restrict__ wa,
                                            const float* __restrict__ wb,
                                            const float* __restrict__ cinter,
                                            const float* __restrict__ cintra,
                                            float* __restrict__ amat,
                                            float* __restrict__ bmat) {
  const int blk = blockIdx.x;
  const int b = blk >> 3, part = blk & 7;
  const int tid = threadIdx.x;
  for (int k = 0; k < 12; ++k) {
    const int g = part * 3072 + k * 256 + tid;
    if (g < 16384) {
      const int m = g >> 7, n = g & 127;
      const float* w = wa + m * 256;
      const float* ci = cinter + (size_t)b * 256 * 128 + n;
      float a[4] = {0.f, 0.f, 0.f, 0.f};
      for (int c0 = 0; c0 < 256; c0 += 4) {
        float4 w4 = *(const float4*)(w + c0);
        a[0] = fmaf(w4.x, ci[(c0 + 0) * 128], a[0]);
        a[1] = fmaf(w4.y, ci[(c0 + 1) * 128], a[1]);
        a[2] = fmaf(w4.z, ci[(c0 + 2) * 128], a[2]);
        a[3] = fmaf(w4.w, ci[(c0 + 3) * 128], a[3]);
      }
      amat[(size_t)b * 16384 + g] = (a[0] + a[1]) + (a[2] + a[3]);
    } else {
      const int i = g - 16384;
      const int m = i >> 6, l = i & 63;
      const float* w = wb + m * 256;
      const float* ct = cintra + (size_t)b * 256 * 64 + l;
      float a[4] = {0.f, 0.f, 0.f, 0.f};
      for (int c0 = 0; c0 < 256; c0 += 4) {
        float4 w4 = *(const float4*)(w + c0);
        a[0] = fmaf(w4.x, ct[(c0 + 0) * 64], a[0]);
        a[1] = fmaf(w4.y, ct[(c0 + 1) * 64], a[1]);
        a[2] = fmaf(w4.z, ct[(c0 + 2) * 64], a[2]);
        a[3] = fmaf(w4.w, ct[(c0 + 3) * 64], a[3]);
      }
      bmat[(size_t)b * 8192 + i] = (a[0] + a[1]) + (a[2] + a[3]);
    }
  }
}

// ---------------------------------------------------------------------------
// K5: an = wn@a (as [n][o]) ; bl = wl@bm (as [l][o])
// ---------------------------------------------------------------------------
__global__ __launch_bounds__(256) void k_nl(const float* __restrict__ wn,
                                            const float* __restrict__ wl,
                                            const float* __restrict__ amat,
                                            const float* __restrict__ bmat,
                                            float* __restrict__ anmat,
                                            float* __restrict__ blmat) {
  const int blk = blockIdx.x;
  const int b = blk >> 3, part = blk & 7;
  const int tid = threadIdx.x;
  for (int k = 0; k < 12; ++k) {
    const int g = part * 3072 + k * 256 + tid;
    if (g < 16384) {
      const int n = g >> 7, o = g & 127;
      const float* w = wn + o * 128;
      const float* av = amat + (size_t)b * 16384 + n;
      float a[4] = {0.f, 0.f, 0.f, 0.f};
      for (int m0 = 0; m0 < 128; m0 += 4) {
        float4 w4 = *(const float4*)(w + m0);
        a[0] = fmaf(w4.x, av[(m0 + 0) * 128], a[0]);
        a[1] = fmaf(w4.y, av[(m0 + 1) * 128], a[1]);
        a[2] = fmaf(w4.z, av[(m0 + 2) * 128], a[2]);
        a[3] = fmaf(w4.w, av[(m0 + 3) * 128], a[3]);
      }
      anmat[(size_t)b * 16384 + g] = (a[0] + a[1]) + (a[2] + a[3]);
    } else {
      const int i = g - 16384;
      const int l = i >> 7, o = i & 127;
      const float* w = wl + o * 128;
      const float* bv = bmat + (size_t)b * 8192 + l;
      float a[4] = {0.f, 0.f, 0.f, 0.f};
      for (int m0 = 0; m0 < 128; m0 += 4) {
        float4 w4 = *(const float4*)(w + m0);
        a[0] = fmaf(w4.x, bv[(m0 + 0) * 64], a[0]);
        a[1] = fmaf(w4.y, bv[(m0 + 1) * 64], a[1]);
        a[2] = fmaf(w4.z, bv[(m0 + 2) * 64], a[2]);
        a[3] = fmaf(w4.w, bv[(m0 + 3) * 64], a[3]);
      }
      blmat[(size_t)b * 8192 + i] = (a[0] + a[1]) + (a[2] + a[3]);
    }
  }
}

// ---------------------------------------------------------------------------
// K6: prep — bf16 (hi/lo where needed) transposed copies of all GEMM operands
// ---------------------------------------------------------------------------
__global__ __launch_bounds__(256) void k_prep(
    const float* __restrict__ wc, const float* __restrict__ wd,
    const float* __restrict__ amat, const float* __restrict__ bmat,
    const float* __restrict__ anmat, const float* __restrict__ blmat,
    u16* __restrict__ wcH, u16* __restrict__ wcL, u16* __restrict__ wdB,
    u16* __restrict__ aTH, u16* __restrict__ aTL,
    u16* __restrict__ bTH, u16* __restrict__ bTL,
    u16* __restrict__ anT, u16* __restrict__ blT) {
  const int i = blockIdx.x * 256 + threadIdx.x;
  if (i < 32768) {
    float v = wc[i]; u16 h = f2b(v); wcH[i] = h; wcL[i] = f2b(v - b2f(h));
  } else if (i < 98304) {
    const int q = i - 32768; wdB[q] = f2b(wd[q]);
  } else if (i < 360448) {
    const int j = i - 98304;
    const int bb = j >> 14, r = j & 16383, n = r >> 7, m = r & 127;
    float v = amat[(size_t)bb * 16384 + m * 128 + n];
    u16 h = f2b(v); aTH[j] = h; aTL[j] = f2b(v - b2f(h));
  } else if (i < 491520) {
    const int j = i - 360448;
    const int bb = j >> 13, r = j & 8191, l = r >> 7, m = r & 127;
    float v = bmat[(size_t)bb * 8192 + m * 64 + l];
    u16 h = f2b(v); bTH[j] = h; bTL[j] = f2b(v - b2f(h));
  } else if (i < 753664) {
    const int j = i - 491520;
    const int bb = j >> 14, r = j & 16383, m = r >> 7, n = r & 127;
    anT[j] = f2b(anmat[(size_t)bb * 16384 + n * 128 + m]);
  } else if (i < 884736) {
    const int j = i - 753664;
    const int bb = j >> 13, r = j & 8191, m = r >> 6, l = r & 63;
    blT[j] = f2b(blmat[(size_t)bb * 8192 + l * 128 + m]);
  }
}

// ---------------------------------------------------------------------------
// K7 (fused MFMA, 8 waves): wave (g=wid&3: 16-col group, h=wid>>2: row half).
// Row-split halves critical path; cross-half softmax combine via LDS.
// LDS 52 KB -> target 3 blocks/CU. Numerics identical to round-2 (hi/lo).
// ---------------------------------------------------------------------------
__global__ __launch_bounds__(512, 6) void k_big(
    const float* __restrict__ x,
    const u16* __restrict__ wcH, const u16* __restrict__ wcL,
    const u16* __restrict__ wdB,
    const u16* __restrict__ aTH, const u16* __restrict__ aTL,
    const u16* __restrict__ bTH, const u16* __restrict__ bTL,
    const u16* __restrict__ anT, const u16* __restrict__ blT,
    const float* __restrict__ bng, const float* __restrict__ bnb,
    const float* __restrict__ bnm, const float* __restrict__ bnv,
    float* __restrict__ out) {
  __shared__ __align__(16) u16 LDS[26624];     // 52 KB
  u16* XtH = LDS;                  // [64][64] x-quarter hi (swizzled)
  u16* XtL = LDS + 4096;           // lo
  u16* ETi = LDS;                  // [64][128] inter exps (after stage 1)
  u16* ETa = LDS;                  // [64][64]  intra exps (after stage 4)
  u16* LTH = LDS + 8192;           // [64][128] logits hi
  u16* LTL = LDS + 16384;          // lo
  u16* FT  = LDS + 8192;           // [64][256] feat (after stage 5)
  float* scL = (float*)(LDS + 24576);   // [256]
  float* biL = (float*)(LDS + 25088);   // [256]
  float* pm  = (float*)(LDS + 25600);   // [2][64] inter pmax
  float* psm = (float*)(LDS + 25856);   // [2][64] inter psum
  float* pm2 = (float*)(LDS + 26112);   // [2][64] intra pmax
  float* ps2 = (float*)(LDS + 26368);   // [2][64] intra psum

  const int tid  = threadIdx.x;
  const int lane = tid & 63;
  const int wid  = tid >> 6;
  const int g    = wid & 3;            // col group (16 p-cols)
  const int h    = wid >> 2;           // row half
  const int l15  = lane & 15;
  const int lg   = lane >> 4;
  const int prow = g * 16 + l15;       // this lane's p-col (0..63)
  const int kf   = lg * 8;
  const int rsw  = (prow & 7) << 3;
  const int blk  = blockIdx.x;
  const int b    = blk >> 7;
  const int p0   = (blk & 127) << 6;
  const f4 zero4 = {0.f, 0.f, 0.f, 0.f};

  // BN constants (R3, no hazard with staging)
  if (tid < 256) {
    const float scv = bng[tid] * rsqrtf(bnv[tid] + 1e-5f);
    scL[tid] = scv;
    biL[tid] = bnb[tid] - bnm[tid] * scv;
  }

  // ---------------- stage 1: L = wc @ X  (hi/lo, 4 K-quarters of 64)
  f4 accL[4];
  #pragma unroll
  for (int t = 0; t < 4; ++t) accL[t] = zero4;
  const float* xb = x + (size_t)b * C_ * N_ + p0;
  const int pp  = tid & 63;
  const int c8  = (tid >> 6) << 3;
  const int sbase = pp * 64 + (c8 ^ ((pp & 7) << 3));
  for (int q = 0; q < 4; ++q) {
    __syncthreads();
    float v[8]; u16 hh[8], ll[8];
    #pragma unroll
    for (int j = 0; j < 8; ++j) v[j] = xb[(size_t)(q * 64 + c8 + j) * N_ + pp];
    #pragma unroll
    for (int j = 0; j < 8; ++j) { hh[j] = f2b(v[j]); ll[j] = f2b(v[j] - b2f(hh[j])); }
    st4(XtH + sbase,     hh[0], hh[1], hh[2], hh[3]);
    st4(XtH + sbase + 4, hh[4], hh[5], hh[6], hh[7]);
    st4(XtL + sbase,     ll[0], ll[1], ll[2], ll[3]);
    st4(XtL + sbase + 4, ll[4], ll[5], ll[6], ll[7]);
    __syncthreads();
    #pragma unroll
    for (int ks = 0; ks < 2; ++ks) {
      const int kk = ks * 32 + kf;
      const bf8 bh = *(const bf8*)(XtH + prow * 64 + (kk ^ rsw));
      const bf8 bl = *(const bf8*)(XtL + prow * 64 + (kk ^ rsw));
      #pragma unroll
      for (int t = 0; t < 4; ++t) {
        const size_t ro = (size_t)(h * 64 + t * 16 + l15) * 256 + q * 64 + kk;
        const bf8 ah = *(const bf8*)(wcH + ro);
        const bf8 al = *(const bf8*)(wcL + ro);
        accL[t] = MFMA(ah, bh, accL[t]);
        accL[t] = MFMA(ah, bl, accL[t]);
        accL[t] = MFMA(al, bh, accL[t]);
      }
    }
  }
  #pragma unroll
  for (int t = 0; t < 4; ++t) {
    const int m0 = h * 64 + t * 16 + lg * 4;
    const int idx = prow * 128 + (m0 ^ rsw);
    u16 hv[4], lv[4];
    #pragma unroll
    for (int r = 0; r < 4; ++r) {
      const float v = accL[t][r];
      hv[r] = f2b(v); lv[r] = f2b(v - b2f(hv[r]));
    }
    st4(LTH + idx, hv[0], hv[1], hv[2], hv[3]);
    st4(LTL + idx, lv[0], lv[1], lv[2], lv[3]);
  }
  __syncthreads();   // LT visible

  // ---------------- stage 2+5 merged: SI = aT@L (4t), SA = bT@L (2t)
  f4 accS[4], accA[2];
  #pragma unroll
  for (int t = 0; t < 4; ++t) accS[t] = zero4;
  accA[0] = zero4; accA[1] = zero4;
  {
    const u16* aHb = aTH + ((size_t)b << 14);
    const u16* aLb = aTL + ((size_t)b << 14);
    const u16* bHb = bTH + ((size_t)b << 13);
    const u16* bLb = bTL + ((size_t)b << 13);
    #pragma unroll
    for (int ks = 0; ks < 4; ++ks) {
      const int kk = ks * 32 + kf;
      const bf8 bh = *(const bf8*)(LTH + prow * 128 + (kk ^ rsw));
      const bf8 bl = *(const bf8*)(LTL + prow * 128 + (kk ^ rsw));
      #pragma unroll
      for (int t = 0; t < 4; ++t) {
        const size_t ro = (size_t)(h * 64 + t * 16 + l15) * 128 + kk;
        const bf8 ah = *(const bf8*)(aHb + ro);
        const bf8 al = *(const bf8*)(aLb + ro);
        accS[t] = MFMA(ah, bh, accS[t]);
        accS[t] = MFMA(ah, bl, accS[t]);
        accS[t] = MFMA(al, bh, accS[t]);
      }
      #pragma unroll
      for (int t = 0; t < 2; ++t) {
        const size_t ro = (size_t)(h * 32 + t * 16 + l15) * 128 + kk;
        const bf8 ah = *(const bf8*)(bHb + ro);
        const bf8 al = *(const bf8*)(bLb + ro);
        accA[t] = MFMA(ah, bh, accA[t]);
        accA[t] = MFMA(ah, bl, accA[t]);
        accA[t] = MFMA(al, bh, accA[t]);
      }
    }
  }
  // inter softmax partials (64 rows of half h per col)
  float mx = -3.0e38f;
  #pragma unroll
  for (int t = 0; t < 4; ++t)
    #pragma unroll
    for (int r = 0; r < 4; ++r) mx = fmaxf(mx, accS[t][r]);
  mx = fmaxf(mx, __shfl_xor(mx, 16));
  mx = fmaxf(mx, __shfl_xor(mx, 32));
  float sum = 0.f;
  #pragma unroll
  for (int t = 0; t < 4; ++t)
    #pragma unroll
    for (int r = 0; r < 4; ++r) {
      const float e = __expf(accS[t][r] - mx);
      accS[t][r] = e; sum += e;
    }
  sum += __shfl_xor(sum, 16);
  sum += __shfl_xor(sum, 32);
  // intra softmax partials (32 rows of half h per col)
  float mx2 = -3.0e38f;
  #pragma unroll
  for (int t = 0; t < 2; ++t)
    #pragma unroll
    for (int r = 0; r < 4; ++r) mx2 = fmaxf(mx2, accA[t][r]);
  mx2 = fmaxf(mx2, __shfl_xor(mx2, 16));
  mx2 = fmaxf(mx2, __shfl_xor(mx2, 32));
  float sum2 = 0.f;
  #pragma unroll
  for (int t = 0; t < 2; ++t)
    #pragma unroll
    for (int r = 0; r < 4; ++r) {
      const float e = __expf(accA[t][r] - mx2);
      accA[t][r] = e; sum2 += e;
    }
  sum2 += __shfl_xor(sum2, 16);
  sum2 += __shfl_xor(sum2, 32);
  if (lane < 16) {
    pm [h * 64 + prow] = mx;  psm[h * 64 + prow] = sum;
    pm2[h * 64 + prow] = mx2; ps2[h * 64 + prow] = sum2;
  }
  __syncthreads();   // partials visible (Xt dead -> ETi region writable)

  // combine inter
  float rcpI, fsc;
  {
    const float m0 = pm[prow], m1 = pm[64 + prow];
    const float M = fmaxf(m0, m1);
    const float S = psm[prow] * __expf(m0 - M) + psm[64 + prow] * __expf(m1 - M);
    rcpI = 1.f / S;
    fsc = __expf(mx - M);
  }
  #pragma unroll
  for (int t = 0; t < 4; ++t) {
    const int n0 = h * 64 + t * 16 + lg * 4;
    const int idx = prow * 128 + (n0 ^ rsw);
    st4(ETi + idx, f2b(accS[t][0] * fsc), f2b(accS[t][1] * fsc),
                   f2b(accS[t][2] * fsc), f2b(accS[t][3] * fsc));
  }
  // combine intra (exps stay in regs, scaled now)
  float rcpT;
  {
    const float m0 = pm2[prow], m1 = pm2[64 + prow];
    const float M = fmaxf(m0, m1);
    const float S = ps2[prow] * __expf(m0 - M) + ps2[64 + prow] * __expf(m1 - M);
    rcpT = 1.f / S;
    const float f2 = __expf(mx2 - M);
    #pragma unroll
    for (int t = 0; t < 2; ++t)
      #pragma unroll
      for (int r = 0; r < 4; ++r) accA[t][r] *= f2;
  }
  __syncthreads();   // ETi visible; all waves past LT reads -> FT writable

  // ---------------- stage 4: XI = anT @ Ei -> FT[:,0:128]
  {
    f4 accX[4];
    #pragma unroll
    for (int t = 0; t < 4; ++t) accX[t] = zero4;
    const u16* anb = anT + ((size_t)b << 14);
    #pragma unroll
    for (int ks = 0; ks < 4; ++ks) {
      const int kk = ks * 32 + kf;
      const bf8 be = *(const bf8*)(ETi + prow * 128 + (kk ^ rsw));
      #pragma unroll
      for (int t = 0; t < 4; ++t) {
        const bf8 a = *(const bf8*)(anb + (size_t)(h * 64 + t * 16 + l15) * 128 + kk);
        accX[t] = MFMA(a, be, accX[t]);
      }
    }
    #pragma unroll
    for (int t = 0; t < 4; ++t) {
      const int d0 = h * 64 + t * 16 + lg * 4;
      const int idx = prow * 256 + (d0 ^ rsw);
      st4(FT + idx, f2b(accX[t][0] * rcpI), f2b(accX[t][1] * rcpI),
                    f2b(accX[t][2] * rcpI), f2b(accX[t][3] * rcpI));
    }
  }
  __syncthreads();   // all waves done reading ETi
  #pragma unroll
  for (int t = 0; t < 2; ++t) {
    const int l0 = h * 32 + t * 16 + lg * 4;
    const int idx = prow * 64 + (l0 ^ rsw);
    st4(ETa + idx, f2b(accA[t][0]), f2b(accA[t][1]),
                   f2b(accA[t][2]), f2b(accA[t][3]));
  }
  __syncthreads();   // ETa visible

  // ---------------- stage 7: XT = blT @ Ea -> FT[:,128:256]
  {
    f4 accT[4];
    #pragma unroll
    for (int t = 0; t < 4; ++t) accT[t] = zero4;
    const u16* blb = blT + ((size_t)b << 13);
    #pragma unroll
    for (int ks = 0; ks < 2; ++ks) {
      const int kk = ks * 32 + kf;
      const bf8 be = *(const bf8*)(ETa + prow * 64 + (kk ^ rsw));
      #pragma unroll
      for (int t = 0; t < 4; ++t) {
        const bf8 a = *(const bf8*)(blb + (size_t)(h * 64 + t * 16 + l15) * 64 + kk);
        accT[t] = MFMA(a, be, accT[t]);
      }
    }
    #pragma unroll
    for (int t = 0; t < 4; ++t) {
      const int d0 = 128 + h * 64 + t * 16 + lg * 4;
      const int idx = prow * 256 + (d0 ^ rsw);
      st4(FT + idx, f2b(accT[t][0] * rcpT), f2b(accT[t][1] * rcpT),
                    f2b(accT[t][2] * rcpT), f2b(accT[t][3] * rcpT));
    }
  }
  __syncthreads();   // FT fully visible

  // ---------------- stage 8: Y = wd @ F ; BN + residual + leaky
  f4 acc8[8];
  #pragma unroll
  for (int t = 0; t < 8; ++t) acc8[t] = zero4;
  #pragma unroll
  for (int ks = 0; ks < 8; ++ks) {
    const int kk = ks * 32 + kf;
    const bf8 bfr = *(const bf8*)(FT + prow * 256 + (kk ^ rsw));
    #pragma unroll
    for (int t = 0; t < 8; ++t) {
      const bf8 a = *(const bf8*)(wdB + (size_t)(h * 128 + t * 16 + l15) * 256 + kk);
      acc8[t] = MFMA(a, bfr, acc8[t]);
    }
  }
  const size_t pcol = (size_t)p0 + prow;
  #pragma unroll
  for (int t = 0; t < 8; ++t) {
    #pragma unroll
    for (int r = 0; r < 4; ++r) {
      const int c = h * 128 + t * 16 + lg * 4 + r;
      const size_t o = (((size_t)b * 256 + c) << 13) + pcol;
      const float z = x[o] + acc8[t][r] * scL[c] + biL[c];
      out[o] = z > 0.f ? z : 0.2f * z;
    }
  }
}

// ---------------------------------------------------------------------------
extern "C" void kernel_launch(void* const* d_in, const int* in_sizes, int n_in,
                              void* d_out, int out_size, void* d_ws, size_t ws_size,
                              hipStream_t stream) {
  const float* x      = (const float*)d_in[0];
  const float* curves = (const float*)d_in[1];
  const float* w_att  = (const float*)d_in[2];
  const float* wa     = (const float*)d_in[3];
  const float* wb     = (const float*)d_in[4];
  const float* wc     = (const float*)d_in[5];
  const float* wn     = (const float*)d_in[6];
  const float* wl     = (const float*)d_in[7];
  const float* wd     = (const float*)d_in[8];
  const float* bng    = (const float*)d_in[9];
  const float* bnb    = (const float*)d_in[10];
  const float* bnm    = (const float*)d_in[11];
  const float* bnv    = (const float*)d_in[12];
  float* out = (float*)d_out;
  float* ws  = (float*)d_ws;

  float* att    = ws;
  float* smi    = ws + 131072;
  float* sma    = ws + 262144;
  float* cinter = ws + 393216;
  float* cintra = ws + 917504;
  float* amat   = ws + 1179648;
  float* bmat   = ws + 1441792;
  float* anmat  = ws + 1572864;
  float* blmat  = ws + 1835008;

  u16* wsb  = (u16*)d_ws;
  u16* wcH  = wsb;
  u16* wcL  = wsb + 32768;
  u16* wdB  = wsb + 65536;
  u16* aTHp = wsb + 131072;
  u16* aTLp = wsb + 393216;
  u16* bTHp = wsb + 655360;
  u16* bTLp = wsb + 786432;
  u16* anTp = wsb + 917504;
  u16* blTp = wsb + 1179648;

  k_att    <<<dim3(B_ * 32),  dim3(256), 0, stream>>>(curves, w_att, att);
  k_softmax<<<dim3(B_),       dim3(256), 0, stream>>>(att, smi, sma);
  k_agg    <<<dim3(B_ * C_),  dim3(256), 0, stream>>>(curves, smi, sma, cinter, cintra);
  k_ab     <<<dim3(B_ * 8),   dim3(256), 0, stream>>>(wa, wb, cinter, cintra, amat, bmat);
  k_nl     <<<dim3(B_ * 8),   dim3(256), 0, stream>>>(wn, wl, amat, bmat, anmat, blmat);
  k_prep   <<<dim3(3456),     dim3(256), 0, stream>>>(wc, wd, amat, bmat, anmat, blmat,
                                                      wcH, wcL, wdB, aTHp, aTLp,
                                                      bTHp, bTLp, anTp, blTp);
  k_big    <<<dim3(B_ * 128), dim3(512), 0, stream>>>(x, wcH, wcL, wdB, aTHp, aTLp,
                                                      bTHp, bTLp, anTp, blTp,
                                                      bng, bnb, bnm, bnv, out);
}

// Round 4
// 597.575 us; speedup vs baseline: 1.1009x; 1.1009x over previous
//
#include <hip/hip_runtime.h>
#include <hip/hip_bf16.h>
#include <cstdint>

#define B_   16
#define C_   256
#define N_   8192
#define CN_  128
#define CL_  64
#define MID_ 128

typedef unsigned short u16;
typedef __attribute__((ext_vector_type(8))) short bf8;
typedef __attribute__((ext_vector_type(4))) float f4;

#define MFMA(a, bb, c) __builtin_amdgcn_mfma_f32_16x16x32_bf16(a, bb, c, 0, 0, 0)

__device__ inline u16 f2b(float v) {
  uint32_t b = __builtin_bit_cast(uint32_t, v);
  uint32_t r = (b + 0x7FFFu + ((b >> 16) & 1u)) >> 16;
  return (u16)r;
}
__device__ inline float b2f(u16 u) {
  uint32_t b = ((uint32_t)u) << 16;
  return __builtin_bit_cast(float, b);
}
__device__ inline void st4(u16* p, u16 a, u16 b, u16 c, u16 d) {
  unsigned long long v = (unsigned long long)a | ((unsigned long long)b << 16) |
                         ((unsigned long long)c << 32) | ((unsigned long long)d << 48);
  *(unsigned long long*)p = v;
}

// ---------------------------------------------------------------------------
// K1: att[b,n,l] = sum_c w_att[c] * curves[b,c,n,l]   (float4 streaming)
// grid B*8, block 256: each thread owns 4 contiguous [n,l] elems
// ---------------------------------------------------------------------------
__global__ __launch_bounds__(256) void k_att(const float* __restrict__ curves,
                                             const float* __restrict__ w_att,
                                             float* __restrict__ att) {
  const int blk = blockIdx.x;
  const int b = blk >> 3, seg = blk & 7;
  const int e4 = seg * 1024 + threadIdx.x * 4;
  const float* cb = curves + (size_t)b * C_ * CN_ * CL_ + e4;
  float4 a = {0.f, 0.f, 0.f, 0.f};
  for (int c = 0; c < C_; ++c) {
    const float w = w_att[c];
    float4 v = *(const float4*)&cb[(size_t)c * 8192];
    a.x = fmaf(w, v.x, a.x);
    a.y = fmaf(w, v.y, a.y);
    a.z = fmaf(w, v.z, a.z);
    a.w = fmaf(w, v.w, a.w);
  }
  *(float4*)&att[b * 8192 + e4] = a;
}

// ---------------------------------------------------------------------------
// K2: dual softmax of att
// ---------------------------------------------------------------------------
__global__ __launch_bounds__(256) void k_softmax(const float* __restrict__ att,
                                                 float* __restrict__ smi,
                                                 float* __restrict__ sma) {
  __shared__ float T[CN_ * CL_];
  __shared__ float rmax[CN_], rrcp[CN_], cmax[CL_], crcp[CL_];
  const int b = blockIdx.x;
  const int tid = threadIdx.x;
  for (int idx = tid; idx < CN_ * CL_; idx += 256) T[idx] = att[b * 8192 + idx];
  __syncthreads();
  if (tid < 128) {
    const int n = tid;
    float mx = -1e30f;
    for (int l = 0; l < CL_; ++l) mx = fmaxf(mx, T[n * 64 + l]);
    float s = 0.f;
    for (int l = 0; l < CL_; ++l) s += __expf(T[n * 64 + l] - mx);
    rmax[n] = mx; rrcp[n] = 1.f / s;
  } else if (tid < 192) {
    const int l = tid - 128;
    float mx = -1e30f;
    for (int n = 0; n < CN_; ++n) mx = fmaxf(mx, T[n * 64 + l]);
    float s = 0.f;
    for (int n = 0; n < CN_; ++n) s += __expf(T[n * 64 + l] - mx);
    cmax[l] = mx; crcp[l] = 1.f / s;
  }
  __syncthreads();
  for (int idx = tid; idx < CN_ * CL_; idx += 256) {
    const int n = idx >> 6, l = idx & 63;
    const float v = T[idx];
    smi[b * 8192 + idx] = __expf(v - rmax[n]) * rrcp[n];
    sma[b * 8192 + idx] = __expf(v - cmax[l]) * crcp[l];
  }
}

// ---------------------------------------------------------------------------
// K3: curve aggregation
// ---------------------------------------------------------------------------
__global__ __launch_bounds__(256) void k_agg(const float* __restrict__ curves,
                                             const float* __restrict__ smi,
                                             const float* __restrict__ sma,
                                             float* __restrict__ cinter,
                                             float* __restrict__ cintra) {
  __shared__ float P[CN_ * CL_];
  const int blk = blockIdx.x;
  const int b = blk >> 8, c = blk & 255;
  const int tid = threadIdx.x;
  const float* src = curves + (size_t)(b * 256 + c) * 8192;
  for (int i4 = tid; i4 < 2048; i4 += 256)
    *(float4*)&P[i4 * 4] = *(const float4*)&src[i4 * 4];
  __syncthreads();
  if (tid < 128) {
    const int n = tid;
    const float* sp = smi + (size_t)(b * 128 + n) * 64;
    float a[4] = {0.f, 0.f, 0.f, 0.f};
    for (int l0 = 0; l0 < 64; l0 += 4) {
      float4 pv = *(const float4*)&P[n * 64 + l0];
      float4 sv = *(const float4*)&sp[l0];
      a[0] = fmaf(pv.x, sv.x, a[0]);
      a[1] = fmaf(pv.y, sv.y, a[1]);
      a[2] = fmaf(pv.z, sv.z, a[2]);
      a[3] = fmaf(pv.w, sv.w, a[3]);
    }
    cinter[(size_t)(b * 256 + c) * 128 + n] = (a[0] + a[1]) + (a[2] + a[3]);
  } else if (tid < 192) {
    const int l = tid - 128;
    float a[4] = {0.f, 0.f, 0.f, 0.f};
    for (int n0 = 0; n0 < 128; n0 += 4) {
      a[0] = fmaf(P[(n0 + 0) * 64 + l], sma[(size_t)(b * 128 + n0 + 0) * 64 + l], a[0]);
      a[1] = fmaf(P[(n0 + 1) * 64 + l], sma[(size_t)(b * 128 + n0 + 1) * 64 + l], a[1]);
      a[2] = fmaf(P[(n0 + 2) * 64 + l], sma[(size_t)(b * 128 + n0 + 2) * 64 + l], a[2]);
      a[3] = fmaf(P[(n0 + 3) * 64 + l], sma[(size_t)(b * 128 + n0 + 3) * 64 + l], a[3]);
    }
    cintra[(size_t)(b * 256 + c) * 64 + l] = (a[0] + a[1]) + (a[2] + a[3]);
  }
}

// ---------------------------------------------------------------------------
// K4: a = wa@cinter ; bm = wb@cintra
// ---------------------------------------------------------------------------
__global__ __launch_bounds__(256) void k_ab(const float* __restrict__ wa,
                                            const float* __restrict__ wb,
                                            const float* __restrict__ cinter,
                                            const float* __restrict__ cintra,
                                            float* __restrict__ amat,
                                            float* __restrict__ bmat) {
  const int blk = blockIdx.x;
  const int b = blk >> 3, part = blk & 7;
  const int tid = threadIdx.x;
  for (int k = 0; k < 12; ++k) {
    const int g = part * 3072 + k * 256 + tid;
    if (g < 16384) {
      const int m = g >> 7, n = g & 127;
      const float* w = wa + m * 256;
      const float* ci = cinter + (size_t)b * 256 * 128 + n;
      float a[4] = {0.f, 0.f, 0.f, 0.f};
      for (int c0 = 0; c0 < 256; c0 += 4) {
        float4 w4 = *(const float4*)(w + c0);
        a[0] = fmaf(w4.x, ci[(c0 + 0) * 128], a[0]);
        a[1] = fmaf(w4.y, ci[(c0 + 1) * 128], a[1]);
        a[2] = fmaf(w4.z, ci[(c0 + 2) * 128], a[2]);
        a[3] = fmaf(w4.w, ci[(c0 + 3) * 128], a[3]);
      }
      amat[(size_t)b * 16384 + g] = (a[0] + a[1]) + (a[2] + a[3]);
    } else {
      const int i = g - 16384;
      const int m = i >> 6, l = i & 63;
      const float* w = wb + m * 256;
      const float* ct = cintra + (size_t)b * 256 * 64 + l;
      float a[4] = {0.f, 0.f, 0.f, 0.f};
      for (int c0 = 0; c0 < 256; c0 += 4) {
        float4 w4 = *(const float4*)(w + c0);
        a[0] = fmaf(w4.x, ct[(c0 + 0) * 64], a[0]);
        a[1] = fmaf(w4.y, ct[(c0 + 1) * 64], a[1]);
        a[2] = fmaf(w4.z, ct[(c0 + 2) * 64], a[2]);
        a[3] = fmaf(w4.w, ct[(c0 + 3) * 64], a[3]);
      }
      bmat[(size_t)b * 8192 + i] = (a[0] + a[1]) + (a[2] + a[3]);
    }
  }
}

// ---------------------------------------------------------------------------
// K5: an[b,n,o] = sum_m wn[o,m] a[b,m,n] ; bl[b,l,o] = sum_m wl[o,m] bm[b,m,l]
// ---------------------------------------------------------------------------
__global__ __launch_bounds__(256) void k_nl(const float* __restrict__ wn,
                                            const float* __restrict__ wl,
                                            const float* __restrict__ amat,
                                            const float* __restrict__ bmat,
                                            float* __restrict__ anmat,
                                            float* __restrict__ blmat) {
  const int blk = blockIdx.x;
  const int b = blk >> 3, part = blk & 7;
  const int tid = threadIdx.x;
  for (int k = 0; k < 12; ++k) {
    const int g = part * 3072 + k * 256 + tid;
    if (g < 16384) {
      const int n = g >> 7, o = g & 127;
      const float* w = wn + o * 128;
      const float* av = amat + (size_t)b * 16384 + n;
      float a[4] = {0.f, 0.f, 0.f, 0.f};
      for (int m0 = 0; m0 < 128; m0 += 4) {
        float4 w4 = *(const float4*)(w + m0);
        a[0] = fmaf(w4.x, av[(m0 + 0) * 128], a[0]);
        a[1] = fmaf(w4.y, av[(m0 + 1) * 128], a[1]);
        a[2] = fmaf(w4.z, av[(m0 + 2) * 128], a[2]);
        a[3] = fmaf(w4.w, av[(m0 + 3) * 128], a[3]);
      }
      anmat[(size_t)b * 16384 + g] = (a[0] + a[1]) + (a[2] + a[3]);
    } else {
      const int i = g - 16384;
      const int l = i >> 7, o = i & 127;
      const float* w = wl + o * 128;
      const float* bv = bmat + (size_t)b * 8192 + l;
      float a[4] = {0.f, 0.f, 0.f, 0.f};
      for (int m0 = 0; m0 < 128; m0 += 4) {
        float4 w4 = *(const float4*)(w + m0);
        a[0] = fmaf(w4.x, bv[(m0 + 0) * 64], a[0]);
        a[1] = fmaf(w4.y, bv[(m0 + 1) * 64], a[1]);
        a[2] = fmaf(w4.z, bv[(m0 + 2) * 64], a[2]);
        a[3] = fmaf(w4.w, bv[(m0 + 3) * 64], a[3]);
      }
      blmat[(size_t)b * 8192 + i] = (a[0] + a[1]) + (a[2] + a[3]);
    }
  }
}

// ---------------------------------------------------------------------------
// K6: fold weights per batch.
//   An[n][c] = sum_m a[m][n] wc[m][c]      (hi/lo)  [128][256]
//   Bl[l][c] = sum_m bm[m][l] wc[m][c]     (hi/lo)  [ 64][256]
//   Wy[c][k] : k<128 -> sum_o wd[c][o] an[n=k][o]; k>=128 -> sum_o wd[c][128+o] bl[l=k-128][o]
// grid 16*24 blocks: tile 0-7 An (n-half x c-quarter), 8-11 Bl (c-quarter),
// 12-19 WN (c-quarter x n-half), 20-23 WL (c-quarter). K=128 in 2 halves.
// Generic: O[r][cc] = sum_k S1[k][r] * S2[k][cc], 64x64 tile, r = lane dim.
// ---------------------------------------------------------------------------
__global__ __launch_bounds__(256) void k_fold(
    const float* __restrict__ wc, const float* __restrict__ wd,
    const float* __restrict__ amat, const float* __restrict__ bmat,
    const float* __restrict__ anmat, const float* __restrict__ blmat,
    u16* __restrict__ AnH, u16* __restrict__ AnL,
    u16* __restrict__ BlH, u16* __restrict__ BlL,
    u16* __restrict__ Wy) {
  __shared__ float S1[64 * 65], S2[64 * 65];
  const int blk = blockIdx.x;
  const int b = blk / 24, tile = blk - b * 24;
  const int tid = threadIdx.x;
  const int r = tid & 63, c4 = tid >> 6;
  float acc[16];
  #pragma unroll
  for (int i = 0; i < 16; ++i) acc[i] = 0.f;

  int n0 = 0, c0 = 0, type;
  if (tile < 8)       { type = 0; n0 = (tile >> 2) * 64; c0 = (tile & 3) * 64; }
  else if (tile < 12) { type = 1; c0 = (tile - 8) * 64; }
  else if (tile < 20) { type = 2; c0 = ((tile - 12) >> 1) * 64; n0 = ((tile - 12) & 1) * 64; }
  else                { type = 3; c0 = (tile - 20) * 64; }

  for (int kh = 0; kh < 2; ++kh) {
    __syncthreads();
    if (type == 0) {            // S1=wc[m][c0+j], S2=a[m][n0+j]
      for (int it = 0; it < 16; ++it) {
        const int flat = it * 256 + tid, ml = flat >> 6, j = flat & 63;
        const int m = kh * 64 + ml;
        S1[ml * 65 + j] = wc[m * 256 + c0 + j];
        S2[ml * 65 + j] = amat[(size_t)b * 16384 + m * 128 + n0 + j];
      }
    } else if (type == 1) {     // S1=wc, S2=bm[m][j]
      for (int it = 0; it < 16; ++it) {
        const int flat = it * 256 + tid, ml = flat >> 6, j = flat & 63;
        const int m = kh * 64 + ml;
        S1[ml * 65 + j] = wc[m * 256 + c0 + j];
        S2[ml * 65 + j] = bmat[(size_t)b * 8192 + m * 64 + j];
      }
    } else if (type == 2) {     // S1=an[n0+i][o], S2=wd[c0+i][o]
      for (int it = 0; it < 16; ++it) {
        const int flat = it * 256 + tid, ol = flat & 63, i2 = flat >> 6;
        const int o = kh * 64 + ol;
        S1[ol * 65 + i2] = anmat[(size_t)b * 16384 + (n0 + i2) * 128 + o];
        S2[ol * 65 + i2] = wd[(c0 + i2) * 256 + o];
      }
    } else {                    // S1=bl[i][o], S2=wd[c0+i][128+o]
      for (int it = 0; it < 16; ++it) {
        const int flat = it * 256 + tid, ol = flat & 63, i2 = flat >> 6;
        const int o = kh * 64 + ol;
        S1[ol * 65 + i2] = blmat[(size_t)b * 8192 + i2 * 128 + o];
        S2[ol * 65 + i2] = wd[(c0 + i2) * 256 + 128 + o];
      }
    }
    __syncthreads();
    for (int k = 0; k < 64; ++k) {
      const float va = S1[k * 65 + r];
      #pragma unroll
      for (int cc = 0; cc < 16; ++cc)
        acc[cc] = fmaf(va, S2[k * 65 + c4 * 16 + cc], acc[cc]);
    }
  }

  if (type == 0) {        // O[c'][n'] -> An[n0+n'][c0+c'] hi/lo
    #pragma unroll
    for (int cc = 0; cc < 16; ++cc) {
      const float v = acc[cc];
      const u16 h = f2b(v);
      const size_t o = (size_t)b * 32768 + (n0 + c4 * 16 + cc) * 256 + c0 + r;
      AnH[o] = h; AnL[o] = f2b(v - b2f(h));
    }
  } else if (type == 1) { // O[c'][l'] -> Bl[l'][c0+c'] hi/lo
    #pragma unroll
    for (int cc = 0; cc < 16; ++cc) {
      const float v = acc[cc];
      const u16 h = f2b(v);
      const size_t o = (size_t)b * 16384 + (c4 * 16 + cc) * 256 + c0 + r;
      BlH[o] = h; BlL[o] = f2b(v - b2f(h));
    }
  } else if (type == 2) { // O[n'][c'] -> Wy[c0+c'][n0+n']
    #pragma unroll
    for (int cc = 0; cc < 16; ++cc)
      Wy[(size_t)b * 49152 + (c0 + c4 * 16 + cc) * 192 + n0 + r] = f2b(acc[cc]);
  } else {                // O[l'][c'] -> Wy[c0+c'][128+l']
    #pragma unroll
    for (int cc = 0; cc < 16; ++cc)
      Wy[(size_t)b * 49152 + (c0 + c4 * 16 + cc) * 192 + 128 + r] = f2b(acc[cc]);
  }
}

// ---------------------------------------------------------------------------
// K7 (fused, folded weights): per 128-point tile, 4 waves x 2 p-subtiles.
//   SI = An@X (hi/lo), SA = Bl@X (hi/lo)  [shared X staging, K=256 in quarters]
//   wave-local softmax over n (128) and l (64)  ->  E = [Ei*rcpI ; Ea*rcpT]
//   y = Wy@E (K=192), BN + residual + leaky.
// LDS 50 KB -> 3 blocks/CU.
// ---------------------------------------------------------------------------
__global__ __launch_bounds__(256, 3) void k_big(
    const float* __restrict__ x,
    const u16* __restrict__ AnH, const u16* __restrict__ AnL,
    const u16* __restrict__ BlH, const u16* __restrict__ BlL,
    const u16* __restrict__ Wy,
    const float* __restrict__ bng, const float* __restrict__ bnb,
    const float* __restrict__ bnm, const float* __restrict__ bnv,
    float* __restrict__ out) {
  __shared__ __align__(16) u16 LDS[25600];   // 50 KB
  u16* XqH = LDS;                    // [128][64] swizzled
  u16* XqL = LDS + 8192;
  u16* E   = LDS;                    // [128][192] swizzled (overlays Xq)
  float* scL = (float*)(LDS + 24576);  // [256]
  float* biL = (float*)(LDS + 25088);  // [256]

  const int tid  = threadIdx.x;
  const int lane = tid & 63;
  const int wid  = tid >> 6;
  const int l15  = lane & 15;
  const int lg   = lane >> 4;
  const int kf   = lg * 8;
  const int wp0  = wid * 32;
  const int p0_  = wp0 + l15;        // subtile 0 p-row
  const int p1_  = p0_ + 16;         // subtile 1
  const int rsw  = (l15 & 7) << 3;   // swizzle (same for both subtiles)

  const int wg  = ((blockIdx.x & 7) << 7) + (blockIdx.x >> 3);   // XCD swizzle
  const int b   = wg >> 6;
  const int p0g = (wg & 63) << 7;

  const u16* AnHb = AnH + ((size_t)b << 15);
  const u16* AnLb = AnL + ((size_t)b << 15);
  const u16* BlHb = BlH + ((size_t)b << 14);
  const u16* BlLb = BlL + ((size_t)b << 14);
  const u16* Wyb  = Wy  + (size_t)b * 49152;
  const f4 zero4 = {0.f, 0.f, 0.f, 0.f};

  // BN constants
  {
    const float scv = bng[tid] * rsqrtf(bnv[tid] + 1e-5f);
    scL[tid] = scv;
    biL[tid] = bnb[tid] - bnm[tid] * scv;
  }

  // ---------------- SI (8t x 2s) and SA (4t x 2s), K=256 in 4 quarters
  f4 accS[8][2], accA[4][2];
  #pragma unroll
  for (int t = 0; t < 8; ++t) { accS[t][0] = zero4; accS[t][1] = zero4; }
  #pragma unroll
  for (int t = 0; t < 4; ++t) { accA[t][0] = zero4; accA[t][1] = zero4; }

  const float* xb = x + (size_t)b * C_ * N_ + p0g;
  const int pp  = tid & 127;
  const int ch  = tid >> 7;                 // c-half of the quarter
  const int swp = (pp & 7) << 3;

  for (int q = 0; q < 4; ++q) {
    __syncthreads();
    #pragma unroll
    for (int jc = 0; jc < 8; ++jc) {
      const int cb = ch * 32 + jc * 4;
      float v0 = xb[(size_t)(q * 64 + cb + 0) * N_ + pp];
      float v1 = xb[(size_t)(q * 64 + cb + 1) * N_ + pp];
      float v2 = xb[(size_t)(q * 64 + cb + 2) * N_ + pp];
      float v3 = xb[(size_t)(q * 64 + cb + 3) * N_ + pp];
      const u16 h0 = f2b(v0), h1 = f2b(v1), h2 = f2b(v2), h3 = f2b(v3);
      const int idx = pp * 64 + (cb ^ swp);
      st4(XqH + idx, h0, h1, h2, h3);
      st4(XqL + idx, f2b(v0 - b2f(h0)), f2b(v1 - b2f(h1)),
                     f2b(v2 - b2f(h2)), f2b(v3 - b2f(h3)));
    }
    __syncthreads();
    #pragma unroll
    for (int ks = 0; ks < 2; ++ks) {
      const int kk = ks * 32 + kf;
      const bf8 bh0 = *(const bf8*)(XqH + p0_ * 64 + (kk ^ rsw));
      const bf8 bl0 = *(const bf8*)(XqL + p0_ * 64 + (kk ^ rsw));
      const bf8 bh1 = *(const bf8*)(XqH + p1_ * 64 + (kk ^ rsw));
      const bf8 bl1 = *(const bf8*)(XqL + p1_ * 64 + (kk ^ rsw));
      #pragma unroll
      for (int t = 0; t < 8; ++t) {
        const size_t ro = (size_t)(t * 16 + l15) * 256 + q * 64 + kk;
        const bf8 ah = *(const bf8*)(AnHb + ro);
        const bf8 al = *(const bf8*)(AnLb + ro);
        accS[t][0] = MFMA(ah, bh0, accS[t][0]);
        accS[t][0] = MFMA(ah, bl0, accS[t][0]);
        accS[t][0] = MFMA(al, bh0, accS[t][0]);
        accS[t][1] = MFMA(ah, bh1, accS[t][1]);
        accS[t][1] = MFMA(ah, bl1, accS[t][1]);
        accS[t][1] = MFMA(al, bh1, accS[t][1]);
      }
      #pragma unroll
      for (int t = 0; t < 4; ++t) {
        const size_t ro = (size_t)(t * 16 + l15) * 256 + q * 64 + kk;
        const bf8 ah = *(const bf8*)(BlHb + ro);
        const bf8 al = *(const bf8*)(BlLb + ro);
        accA[t][0] = MFMA(ah, bh0, accA[t][0]);
        accA[t][0] = MFMA(ah, bl0, accA[t][0]);
        accA[t][0] = MFMA(al, bh0, accA[t][0]);
        accA[t][1] = MFMA(ah, bh1, accA[t][1]);
        accA[t][1] = MFMA(ah, bl1, accA[t][1]);
        accA[t][1] = MFMA(al, bh1, accA[t][1]);
      }
    }
  }
  __syncthreads();   // Xq dead -> E region writable

  // ---------------- softmax (wave-local) + E writes
  #pragma unroll
  for (int s = 0; s < 2; ++s) {
    const int ps = s ? p1_ : p0_;
    float mx = -3.0e38f;
    #pragma unroll
    for (int t = 0; t < 8; ++t)
      #pragma unroll
      for (int r = 0; r < 4; ++r) mx = fmaxf(mx, accS[t][s][r]);
    mx = fmaxf(mx, __shfl_xor(mx, 16));
    mx = fmaxf(mx, __shfl_xor(mx, 32));
    float sum = 0.f;
    #pragma unroll
    for (int t = 0; t < 8; ++t)
      #pragma unroll
      for (int r = 0; r < 4; ++r) {
        const float e = __expf(accS[t][s][r] - mx);
        accS[t][s][r] = e; sum += e;
      }
    sum += __shfl_xor(sum, 16);
    sum += __shfl_xor(sum, 32);
    const float rcp = 1.f / sum;
    #pragma unroll
    for (int t = 0; t < 8; ++t) {
      const int idx = ps * 192 + ((t * 16 + lg * 4) ^ rsw);
      st4(E + idx, f2b(accS[t][s][0] * rcp), f2b(accS[t][s][1] * rcp),
                   f2b(accS[t][s][2] * rcp), f2b(accS[t][s][3] * rcp));
    }
    float mx2 = -3.0e38f;
    #pragma unroll
    for (int t = 0; t < 4; ++t)
      #pragma unroll
      for (int r = 0; r < 4; ++r) mx2 = fmaxf(mx2, accA[t][s][r]);
    mx2 = fmaxf(mx2, __shfl_xor(mx2, 16));
    mx2 = fmaxf(mx2, __shfl_xor(mx2, 32));
    float sum2 = 0.f;
    #pragma unroll
    for (int t = 0; t < 4; ++t)
      #pragma unroll
      for (int r = 0; r < 4; ++r) {
        const float e = __expf(accA[t][s][r] - mx2);
        accA[t][s][r] = e; sum2 += e;
      }
    sum2 += __shfl_xor(sum2, 16);
    sum2 += __shfl_xor(sum2, 32);
    const float rcp2 = 1.f / sum2;
    #pragma unroll
    for (int t = 0; t < 4; ++t) {
      const int idx = ps * 192 + (128 + ((t * 16 + lg * 4) ^ rsw));
      st4(E + idx, f2b(accA[t][s][0] * rcp2), f2b(accA[t][s][1] * rcp2),
                   f2b(accA[t][s][2] * rcp2), f2b(accA[t][s][3] * rcp2));
    }
  }
  __syncthreads();   // E visible

  // ---------------- y = Wy @ E (K=192), two c-halves
  #pragma unroll
  for (int hh = 0; hh < 2; ++hh) {
    f4 a8[8][2];
    #pragma unroll
    for (int t = 0; t < 8; ++t) { a8[t][0] = zero4; a8[t][1] = zero4; }
    #pragma unroll
    for (int ks = 0; ks < 6; ++ks) {
      const int kk = ks * 32 + kf;
      const int ko = (kk < 128) ? (kk ^ rsw) : (128 + ((kk - 128) ^ rsw));
      const bf8 b0 = *(const bf8*)(E + p0_ * 192 + ko);
      const bf8 b1 = *(const bf8*)(E + p1_ * 192 + ko);
      #pragma unroll
      for (int t = 0; t < 8; ++t) {
        const bf8 a = *(const bf8*)(Wyb + (size_t)(hh * 128 + t * 16 + l15) * 192 + kk);
        a8[t][0] = MFMA(a, b0, a8[t][0]);
        a8[t][1] = MFMA(a, b1, a8[t][1]);
      }
    }
    #pragma unroll
    for (int t = 0; t < 8; ++t) {
      #pragma unroll
      for (int r = 0; r < 4; ++r) {
        const int c = hh * 128 + t * 16 + lg * 4 + r;
        const float sc = scL[c], bi = biL[c];
        const size_t o0 = (((size_t)b * 256 + c) << 13) + p0g + p0_;
        const float z0 = x[o0] + a8[t][0][r] * sc + bi;
        out[o0] = z0 > 0.f ? z0 : 0.2f * z0;
        const size_t o1 = o0 + 16;
        const float z1 = x[o1] + a8[t][1][r] * sc + bi;
        out[o1] = z1 > 0.f ? z1 : 0.2f * z1;
      }
    }
  }
}

// ---------------------------------------------------------------------------
extern "C" void kernel_launch(void* const* d_in, const int* in_sizes, int n_in,
                              void* d_out, int out_size, void* d_ws, size_t ws_size,
                              hipStream_t stream) {
  const float* x      = (const float*)d_in[0];
  const float* curves = (const float*)d_in[1];
  const float* w_att  = (const float*)d_in[2];
  const float* wa     = (const float*)d_in[3];
  const float* wb     = (const float*)d_in[4];
  const float* wc     = (const float*)d_in[5];
  const float* wn     = (const float*)d_in[6];
  const float* wl     = (const float*)d_in[7];
  const float* wd     = (const float*)d_in[8];
  const float* bng    = (const float*)d_in[9];
  const float* bnb    = (const float*)d_in[10];
  const float* bnm    = (const float*)d_in[11];
  const float* bnv    = (const float*)d_in[12];
  float* out = (float*)d_out;
  float* ws  = (float*)d_ws;

  // f32 scratch (upper region; live until k_fold consumes them)
  float* att    = ws;                 // dead after k_softmax
  float* smi    = ws + 131072;        // dead after k_agg
  float* sma    = ws + 262144;
  float* cinter = ws + 393216;        // dead after k_ab
  float* cintra = ws + 917504;
  float* amat   = ws + 1179648;
  float* bmat   = ws + 1441792;
  float* anmat  = ws + 1572864;
  float* blmat  = ws + 1835008;       // end 1966080 f32

  // u16 folded buffers overlay f32 region [0, 1179648) — dead by k_fold time
  u16* wsb = (u16*)d_ws;
  u16* AnH = wsb;                     // 524288
  u16* AnL = wsb + 524288;
  u16* BlH = wsb + 1048576;           // 262144
  u16* BlL = wsb + 1310720;
  u16* Wyp = wsb + 1572864;           // 786432 -> end 2359296 u16 = 1179648 f32

  k_att    <<<dim3(B_ * 8),   dim3(256), 0, stream>>>(curves, w_att, att);
  k_softmax<<<dim3(B_),       dim3(256), 0, stream>>>(att, smi, sma);
  k_agg    <<<dim3(B_ * C_),  dim3(256), 0, stream>>>(curves, smi, sma, cinter, cintra);
  k_ab     <<<dim3(B_ * 8),   dim3(256), 0, stream>>>(wa, wb, cinter, cintra, amat, bmat);
  k_nl     <<<dim3(B_ * 8),   dim3(256), 0, stream>>>(wn, wl, amat, bmat, anmat, blmat);
  k_fold   <<<dim3(B_ * 24),  dim3(256), 0, stream>>>(wc, wd, amat, bmat, anmat, blmat,
                                                      AnH, AnL, BlH, BlL, Wyp);
  k_big    <<<dim3(1024),     dim3(256), 0, stream>>>(x, AnH, AnL, BlH, BlL, Wyp,
                                                      bng, bnb, bnm, bnv, out);
}

// Round 6
// 349.868 us; speedup vs baseline: 1.8803x; 1.7080x over previous
//
#include <hip/hip_runtime.h>
#include <hip/hip_bf16.h>
#include <cstdint>

#define B_   16
#define C_   256
#define N_   8192
#define CN_  128
#define CL_  64
#define MID_ 128

typedef unsigned short u16;
typedef __attribute__((ext_vector_type(8))) short bf8;
typedef __attribute__((ext_vector_type(4))) float f4;

#define MFMA(a, bb, c) __builtin_amdgcn_mfma_f32_16x16x32_bf16(a, bb, c, 0, 0, 0)

__device__ inline u16 f2b(float v) {
  uint32_t b = __builtin_bit_cast(uint32_t, v);
  uint32_t r = (b + 0x7FFFu + ((b >> 16) & 1u)) >> 16;
  return (u16)r;
}
__device__ inline float b2f(u16 u) {
  uint32_t b = ((uint32_t)u) << 16;
  return __builtin_bit_cast(float, b);
}
__device__ inline void st4(u16* p, u16 a, u16 b, u16 c, u16 d) {
  unsigned long long v = (unsigned long long)a | ((unsigned long long)b << 16) |
                         ((unsigned long long)c << 32) | ((unsigned long long)d << 48);
  *(unsigned long long*)p = v;
}

// ---------------------------------------------------------------------------
// K1: att[b,n,l] = sum_c w_att[c] * curves[b,c,n,l]   (float4 streaming)
// ---------------------------------------------------------------------------
__global__ __launch_bounds__(256) void k_att(const float* __restrict__ curves,
                                             const float* __restrict__ w_att,
                                             float* __restrict__ att) {
  const int blk = blockIdx.x;
  const int b = blk >> 3, seg = blk & 7;
  const int e4 = seg * 1024 + threadIdx.x * 4;
  const float* cb = curves + (size_t)b * C_ * CN_ * CL_ + e4;
  float4 a = {0.f, 0.f, 0.f, 0.f};
  for (int c = 0; c < C_; ++c) {
    const float w = w_att[c];
    float4 v = *(const float4*)&cb[(size_t)c * 8192];
    a.x = fmaf(w, v.x, a.x);
    a.y = fmaf(w, v.y, a.y);
    a.z = fmaf(w, v.z, a.z);
    a.w = fmaf(w, v.w, a.w);
  }
  *(float4*)&att[b * 8192 + e4] = a;
}

// ---------------------------------------------------------------------------
// K2: dual softmax of att
// ---------------------------------------------------------------------------
__global__ __launch_bounds__(256) void k_softmax(const float* __restrict__ att,
                                                 float* __restrict__ smi,
                                                 float* __restrict__ sma) {
  __shared__ float T[CN_ * CL_];
  __shared__ float rmax[CN_], rrcp[CN_], cmax[CL_], crcp[CL_];
  const int b = blockIdx.x;
  const int tid = threadIdx.x;
  for (int idx = tid; idx < CN_ * CL_; idx += 256) T[idx] = att[b * 8192 + idx];
  __syncthreads();
  if (tid < 128) {
    const int n = tid;
    float mx = -1e30f;
    for (int l = 0; l < CL_; ++l) mx = fmaxf(mx, T[n * 64 + l]);
    float s = 0.f;
    for (int l = 0; l < CL_; ++l) s += __expf(T[n * 64 + l] - mx);
    rmax[n] = mx; rrcp[n] = 1.f / s;
  } else if (tid < 192) {
    const int l = tid - 128;
    float mx = -1e30f;
    for (int n = 0; n < CN_; ++n) mx = fmaxf(mx, T[n * 64 + l]);
    float s = 0.f;
    for (int n = 0; n < CN_; ++n) s += __expf(T[n * 64 + l] - mx);
    cmax[l] = mx; crcp[l] = 1.f / s;
  }
  __syncthreads();
  for (int idx = tid; idx < CN_ * CL_; idx += 256) {
    const int n = idx >> 6, l = idx & 63;
    const float v = T[idx];
    smi[b * 8192 + idx] = __expf(v - rmax[n]) * rrcp[n];
    sma[b * 8192 + idx] = __expf(v - cmax[l]) * crcp[l];
  }
}

// ---------------------------------------------------------------------------
// K3: curve aggregation
// ---------------------------------------------------------------------------
__global__ __launch_bounds__(256) void k_agg(const float* __restrict__ curves,
                                             const float* __restrict__ smi,
                                             const float* __restrict__ sma,
                                             float* __restrict__ cinter,
                                             float* __restrict__ cintra) {
  __shared__ float P[CN_ * CL_];
  const int blk = blockIdx.x;
  const int b = blk >> 8, c = blk & 255;
  const int tid = threadIdx.x;
  const float* src = curves + (size_t)(b * 256 + c) * 8192;
  for (int i4 = tid; i4 < 2048; i4 += 256)
    *(float4*)&P[i4 * 4] = *(const float4*)&src[i4 * 4];
  __syncthreads();
  if (tid < 128) {
    const int n = tid;
    const float* sp = smi + (size_t)(b * 128 + n) * 64;
    float a[4] = {0.f, 0.f, 0.f, 0.f};
    for (int l0 = 0; l0 < 64; l0 += 4) {
      float4 pv = *(const float4*)&P[n * 64 + l0];
      float4 sv = *(const float4*)&sp[l0];
      a[0] = fmaf(pv.x, sv.x, a[0]);
      a[1] = fmaf(pv.y, sv.y, a[1]);
      a[2] = fmaf(pv.z, sv.z, a[2]);
      a[3] = fmaf(pv.w, sv.w, a[3]);
    }
    cinter[(size_t)(b * 256 + c) * 128 + n] = (a[0] + a[1]) + (a[2] + a[3]);
  } else if (tid < 192) {
    const int l = tid - 128;
    float a[4] = {0.f, 0.f, 0.f, 0.f};
    for (int n0 = 0; n0 < 128; n0 += 4) {
      a[0] = fmaf(P[(n0 + 0) * 64 + l], sma[(size_t)(b * 128 + n0 + 0) * 64 + l], a[0]);
      a[1] = fmaf(P[(n0 + 1) * 64 + l], sma[(size_t)(b * 128 + n0 + 1) * 64 + l], a[1]);
      a[2] = fmaf(P[(n0 + 2) * 64 + l], sma[(size_t)(b * 128 + n0 + 2) * 64 + l], a[2]);
      a[3] = fmaf(P[(n0 + 3) * 64 + l], sma[(size_t)(b * 128 + n0 + 3) * 64 + l], a[3]);
    }
    cintra[(size_t)(b * 256 + c) * 64 + l] = (a[0] + a[1]) + (a[2] + a[3]);
  }
}

// ---------------------------------------------------------------------------
// K4: a = wa@cinter ; bm = wb@cintra
// ---------------------------------------------------------------------------
__global__ __launch_bounds__(256) void k_ab(const float* __restrict__ wa,
                                            const float* __restrict__ wb,
                                            const float* __restrict__ cinter,
                                            const float* __restrict__ cintra,
                                            float* __restrict__ amat,
                                            float* __restrict__ bmat) {
  const int blk = blockIdx.x;
  const int b = blk >> 3, part = blk & 7;
  const int tid = threadIdx.x;
  for (int k = 0; k < 12; ++k) {
    const int g = part * 3072 + k * 256 + tid;
    if (g < 16384) {
      const int m = g >> 7, n = g & 127;
      const float* w = wa + m * 256;
      const float* ci = cinter + (size_t)b * 256 * 128 + n;
      float a[4] = {0.f, 0.f, 0.f, 0.f};
      for (int c0 = 0; c0 < 256; c0 += 4) {
        float4 w4 = *(const float4*)(w + c0);
        a[0] = fmaf(w4.x, ci[(c0 + 0) * 128], a[0]);
        a[1] = fmaf(w4.y, ci[(c0 + 1) * 128], a[1]);
        a[2] = fmaf(w4.z, ci[(c0 + 2) * 128], a[2]);
        a[3] = fmaf(w4.w, ci[(c0 + 3) * 128], a[3]);
      }
      amat[(size_t)b * 16384 + g] = (a[0] + a[1]) + (a[2] + a[3]);
    } else {
      const int i = g - 16384;
      const int m = i >> 6, l = i & 63;
      const float* w = wb + m * 256;
      const float* ct = cintra + (size_t)b * 256 * 64 + l;
      float a[4] = {0.f, 0.f, 0.f, 0.f};
      for (int c0 = 0; c0 < 256; c0 += 4) {
        float4 w4 = *(const float4*)(w + c0);
        a[0] = fmaf(w4.x, ct[(c0 + 0) * 64], a[0]);
        a[1] = fmaf(w4.y, ct[(c0 + 1) * 64], a[1]);
        a[2] = fmaf(w4.z, ct[(c0 + 2) * 64], a[2]);
        a[3] = fmaf(w4.w, ct[(c0 + 3) * 64], a[3]);
      }
      bmat[(size_t)b * 8192 + i] = (a[0] + a[1]) + (a[2] + a[3]);
    }
  }
}

// ---------------------------------------------------------------------------
// K5: an[b,n,o] = sum_m wn[o,m] a[b,m,n] ; bl[b,l,o] = sum_m wl[o,m] bm[b,m,l]
// ---------------------------------------------------------------------------
__global__ __launch_bounds__(256) void k_nl(const float* __restrict__ wn,
                                            const float* __restrict__ wl,
                                            const float* __restrict__ amat,
                                            const float* __restrict__ bmat,
                                            float* __restrict__ anmat,
                                            float* __restrict__ blmat) {
  const int blk = blockIdx.x;
  const int b = blk >> 3, part = blk & 7;
  const int tid = threadIdx.x;
  for (int k = 0; k < 12; ++k) {
    const int g = part * 3072 + k * 256 + tid;
    if (g < 16384) {
      const int n = g >> 7, o = g & 127;
      const float* w = wn + o * 128;
      const float* av = amat + (size_t)b * 16384 + n;
      float a[4] = {0.f, 0.f, 0.f, 0.f};
      for (int m0 = 0; m0 < 128; m0 += 4) {
        float4 w4 = *(const float4*)(w + m0);
        a[0] = fmaf(w4.x, av[(m0 + 0) * 128], a[0]);
        a[1] = fmaf(w4.y, av[(m0 + 1) * 128], a[1]);
        a[2] = fmaf(w4.z, av[(m0 + 2) * 128], a[2]);
        a[3] = fmaf(w4.w, av[(m0 + 3) * 128], a[3]);
      }
      anmat[(size_t)b * 16384 + g] = (a[0] + a[1]) + (a[2] + a[3]);
    } else {
      const int i = g - 16384;
      const int l = i >> 7, o = i & 127;
      const float* w = wl + o * 128;
      const float* bv = bmat + (size_t)b * 8192 + l;
      float a[4] = {0.f, 0.f, 0.f, 0.f};
      for (int m0 = 0; m0 < 128; m0 += 4) {
        float4 w4 = *(const float4*)(w + m0);
        a[0] = fmaf(w4.x, bv[(m0 + 0) * 64], a[0]);
        a[1] = fmaf(w4.y, bv[(m0 + 1) * 64], a[1]);
        a[2] = fmaf(w4.z, bv[(m0 + 2) * 64], a[2]);
        a[3] = fmaf(w4.w, bv[(m0 + 3) * 64], a[3]);
      }
      blmat[(size_t)b * 8192 + i] = (a[0] + a[1]) + (a[2] + a[3]);
    }
  }
}

// ---------------------------------------------------------------------------
// K6: fold weights per batch (unchanged).
// ---------------------------------------------------------------------------
__global__ __launch_bounds__(256) void k_fold(
    const float* __restrict__ wc, const float* __restrict__ wd,
    const float* __restrict__ amat, const float* __restrict__ bmat,
    const float* __restrict__ anmat, const float* __restrict__ blmat,
    u16* __restrict__ AnH, u16* __restrict__ AnL,
    u16* __restrict__ BlH, u16* __restrict__ BlL,
    u16* __restrict__ Wy) {
  __shared__ float S1[64 * 65], S2[64 * 65];
  const int blk = blockIdx.x;
  const int b = blk / 24, tile = blk - b * 24;
  const int tid = threadIdx.x;
  const int r = tid & 63, c4 = tid >> 6;
  float acc[16];
  #pragma unroll
  for (int i = 0; i < 16; ++i) acc[i] = 0.f;

  int n0 = 0, c0 = 0, type;
  if (tile < 8)       { type = 0; n0 = (tile >> 2) * 64; c0 = (tile & 3) * 64; }
  else if (tile < 12) { type = 1; c0 = (tile - 8) * 64; }
  else if (tile < 20) { type = 2; c0 = ((tile - 12) >> 1) * 64; n0 = ((tile - 12) & 1) * 64; }
  else                { type = 3; c0 = (tile - 20) * 64; }

  for (int kh = 0; kh < 2; ++kh) {
    __syncthreads();
    if (type == 0) {
      for (int it = 0; it < 16; ++it) {
        const int flat = it * 256 + tid, ml = flat >> 6, j = flat & 63;
        const int m = kh * 64 + ml;
        S1[ml * 65 + j] = wc[m * 256 + c0 + j];
        S2[ml * 65 + j] = amat[(size_t)b * 16384 + m * 128 + n0 + j];
      }
    } else if (type == 1) {
      for (int it = 0; it < 16; ++it) {
        const int flat = it * 256 + tid, ml = flat >> 6, j = flat & 63;
        const int m = kh * 64 + ml;
        S1[ml * 65 + j] = wc[m * 256 + c0 + j];
        S2[ml * 65 + j] = bmat[(size_t)b * 8192 + m * 64 + j];
      }
    } else if (type == 2) {
      for (int it = 0; it < 16; ++it) {
        const int flat = it * 256 + tid, ol = flat & 63, i2 = flat >> 6;
        const int o = kh * 64 + ol;
        S1[ol * 65 + i2] = anmat[(size_t)b * 16384 + (n0 + i2) * 128 + o];
        S2[ol * 65 + i2] = wd[(c0 + i2) * 256 + o];
      }
    } else {
      for (int it = 0; it < 16; ++it) {
        const int flat = it * 256 + tid, ol = flat & 63, i2 = flat >> 6;
        const int o = kh * 64 + ol;
        S1[ol * 65 + i2] = blmat[(size_t)b * 8192 + i2 * 128 + o];
        S2[ol * 65 + i2] = wd[(c0 + i2) * 256 + 128 + o];
      }
    }
    __syncthreads();
    for (int k = 0; k < 64; ++k) {
      const float va = S1[k * 65 + r];
      #pragma unroll
      for (int cc = 0; cc < 16; ++cc)
        acc[cc] = fmaf(va, S2[k * 65 + c4 * 16 + cc], acc[cc]);
    }
  }

  if (type == 0) {
    #pragma unroll
    for (int cc = 0; cc < 16; ++cc) {
      const float v = acc[cc];
      const u16 h = f2b(v);
      const size_t o = (size_t)b * 32768 + (n0 + c4 * 16 + cc) * 256 + c0 + r;
      AnH[o] = h; AnL[o] = f2b(v - b2f(h));
    }
  } else if (type == 1) {
    #pragma unroll
    for (int cc = 0; cc < 16; ++cc) {
      const float v = acc[cc];
      const u16 h = f2b(v);
      const size_t o = (size_t)b * 16384 + (c4 * 16 + cc) * 256 + c0 + r;
      BlH[o] = h; BlL[o] = f2b(v - b2f(h));
    }
  } else if (type == 2) {
    #pragma unroll
    for (int cc = 0; cc < 16; ++cc)
      Wy[(size_t)b * 49152 + (c0 + c4 * 16 + cc) * 192 + n0 + r] = f2b(acc[cc]);
  } else {
    #pragma unroll
    for (int cc = 0; cc < 16; ++cc)
      Wy[(size_t)b * 49152 + (c0 + c4 * 16 + cc) * 192 + 128 + r] = f2b(acc[cc]);
  }
}

// ---------------------------------------------------------------------------
// K7 (fused, LDS-operand GEMM): p-tile 64, 4 waves (wave = 16 p-cols).
// Score: S = [An;Bl](hi/lo) @ X(hi/lo), K=256 in 8 steps of 32, A+X double-
// buffered in LDS (issue-early loads, write-late ds_write, 1 barrier/step).
// Softmax wave-local -> E[64][192] in LDS. Out: y = Wy @ E, K=192 in 6 steps,
// Wy double-buffered. Chunk-XOR swizzles keep all ds_reads <=2-way.
// LDS 67.6 KB -> 2 blocks/CU.
// ---------------------------------------------------------------------------
__global__ __launch_bounds__(256, 2) void k_big(
    const float* __restrict__ x,
    const u16* __restrict__ AnH, const u16* __restrict__ AnL,
    const u16* __restrict__ BlH, const u16* __restrict__ BlL,
    const u16* __restrict__ Wy,
    const float* __restrict__ bng, const float* __restrict__ bnb,
    const float* __restrict__ bnm, const float* __restrict__ bnv,
    float* __restrict__ out) {
  __shared__ __align__(16) u16 LDS[33792];
  float* scL = (float*)(LDS + 32768);
  float* biL = (float*)(LDS + 33280);

  const int tid  = threadIdx.x;
  const int lane = tid & 63;
  const int wid  = tid >> 6;
  const int l15  = lane & 15;
  const int lg   = lane >> 4;
  const int p    = wid * 16 + l15;          // lane's p-col (0..63)
  const int blk  = blockIdx.x;
  const int wg   = ((blk & 7) << 8) | (blk >> 3);   // XCD swizzle (2048 = 8*256)
  const int b    = wg >> 7;
  const int p0g  = (wg & 127) << 6;
  const f4 zero4 = {0.f, 0.f, 0.f, 0.f};

  const u16* AnHb = AnH + ((size_t)b << 15);
  const u16* AnLb = AnL + ((size_t)b << 15);
  const u16* BlHb = BlH + ((size_t)b << 14);
  const u16* BlLb = BlL + ((size_t)b << 14);
  const u16* Wyb  = Wy  + (size_t)b * 49152;

  // BN constants
  {
    const float scv = bng[tid] * rsqrtf(bnv[tid] + 1e-5f);
    scL[tid] = scv;
    biL[tid] = bnb[tid] - bnm[tid] * scv;
  }

  // ---- per-thread staging geometry
  const int xp  = tid & 63;
  const int xkc = tid >> 6;
  const float* xb = x + (size_t)b * C_ * N_ + p0g;
  const int xoff = xp * 32 + ((xkc ^ ((xp >> 1) & 3)) * 8);
  // A: 6 chunks of 16B per thread; 1536 chunks = 2 planes x 192 rows x 4 kc
  const u16* aSrc[6];
  int aLds[6];
  #pragma unroll
  for (int j = 0; j < 6; ++j) {
    const int cid = j * 256 + tid;          // 0..1535
    const int plane = (cid >= 768) ? 1 : 0;
    const int rr = cid - plane * 768;       // FIX: true modulo (was cid & 767)
    const int row = rr >> 2, kc = rr & 3;
    const u16* base;
    if (row < 128) base = (plane ? AnLb : AnHb) + row * 256;
    else           base = (plane ? BlLb : BlHb) + (row - 128) * 256;
    aSrc[j] = base + 8 * (kc ^ ((row >> 1) & 3));
    aLds[j] = plane * 6144 + row * 32 + kc * 8;
  }
  // Wy: 4 chunks per thread; 1024 chunks = 256 rows x 4 kc
  const u16* wSrc[4];
  int wLds[4];
  #pragma unroll
  for (int j = 0; j < 4; ++j) {
    const int cid = j * 256 + tid;
    const int row = cid >> 2, kc = cid & 3;
    wSrc[j] = Wyb + row * 192 + 8 * (kc ^ ((row >> 1) & 3));
    wLds[j] = row * 32 + kc * 8;
  }

  // ================= SCORE PHASE =================
  f4 accS[8], accA[4];
  #pragma unroll
  for (int t = 0; t < 8; ++t) accS[t] = zero4;
  #pragma unroll
  for (int t = 0; t < 4; ++t) accA[t] = zero4;

  bf8 aReg[6];
  float xReg[8];

  // prologue: stage step 0 into buf 0
  #pragma unroll
  for (int j = 0; j < 6; ++j) aReg[j] = *(const bf8*)(aSrc[j]);
  #pragma unroll
  for (int jj = 0; jj < 8; ++jj)
    xReg[jj] = xb[(size_t)(xkc * 8 + jj) * N_ + xp];
  #pragma unroll
  for (int j = 0; j < 6; ++j) *(bf8*)(LDS + aLds[j]) = aReg[j];
  {
    bf8 vh, vl;
    #pragma unroll
    for (int jj = 0; jj < 8; ++jj) {
      const u16 h = f2b(xReg[jj]);
      vh[jj] = (short)h; vl[jj] = (short)f2b(xReg[jj] - b2f(h));
    }
    *(bf8*)(LDS + 24576 + xoff) = vh;
    *(bf8*)(LDS + 24576 + 2048 + xoff) = vl;
  }
  __syncthreads();

  for (int q = 0; q < 8; ++q) {
    const int buf = q & 1;
    if (q < 7) {   // issue-early prefetch of step q+1
      #pragma unroll
      for (int j = 0; j < 6; ++j) aReg[j] = *(const bf8*)(aSrc[j] + (q + 1) * 32);
      #pragma unroll
      for (int jj = 0; jj < 8; ++jj)
        xReg[jj] = xb[(size_t)((q + 1) * 32 + xkc * 8 + jj) * N_ + xp];
    }
    const u16* Ab = LDS + buf * 12288;
    const u16* Xb = LDS + 24576 + buf * 4096;
    const int xsw = (p >> 1) & 3;
    const bf8 xh = *(const bf8*)(Xb + p * 32 + ((lg ^ xsw) * 8));
    const bf8 xl = *(const bf8*)(Xb + 2048 + p * 32 + ((lg ^ xsw) * 8));
    #pragma unroll
    for (int t = 0; t < 8; ++t) {
      const int row = t * 16 + l15;
      const int sw = 8 * (lg ^ ((row >> 1) & 3));
      const bf8 ah = *(const bf8*)(Ab + row * 32 + sw);
      const bf8 al = *(const bf8*)(Ab + 6144 + row * 32 + sw);
      accS[t] = MFMA(ah, xh, accS[t]);
      accS[t] = MFMA(ah, xl, accS[t]);
      accS[t] = MFMA(al, xh, accS[t]);
    }
    #pragma unroll
    for (int t = 0; t < 4; ++t) {
      const int row = 128 + t * 16 + l15;
      const int sw = 8 * (lg ^ ((row >> 1) & 3));
      const bf8 ah = *(const bf8*)(Ab + row * 32 + sw);
      const bf8 al = *(const bf8*)(Ab + 6144 + row * 32 + sw);
      accA[t] = MFMA(ah, xh, accA[t]);
      accA[t] = MFMA(ah, xl, accA[t]);
      accA[t] = MFMA(al, xh, accA[t]);
    }
    if (q < 7) {   // write-late into the other buffer
      u16* An_ = LDS + (buf ^ 1) * 12288;
      #pragma unroll
      for (int j = 0; j < 6; ++j) *(bf8*)(An_ + aLds[j]) = aReg[j];
      bf8 vh, vl;
      #pragma unroll
      for (int jj = 0; jj < 8; ++jj) {
        const u16 h = f2b(xReg[jj]);
        vh[jj] = (short)h; vl[jj] = (short)f2b(xReg[jj] - b2f(h));
      }
      u16* Xn_ = LDS + 24576 + (buf ^ 1) * 4096;
      *(bf8*)(Xn_ + xoff) = vh;
      *(bf8*)(Xn_ + 2048 + xoff) = vl;
    }
    __syncthreads();
  }

  // ================= SOFTMAX (wave-local) + E =================
  u16* E = LDS;   // [64 p][192 j], chunk-XOR by (p&7)
  {
    float mx = -3.0e38f;
    #pragma unroll
    for (int t = 0; t < 8; ++t)
      #pragma unroll
      for (int r = 0; r < 4; ++r) mx = fmaxf(mx, accS[t][r]);
    mx = fmaxf(mx, __shfl_xor(mx, 16));
    mx = fmaxf(mx, __shfl_xor(mx, 32));
    float sum = 0.f;
    #pragma unroll
    for (int t = 0; t < 8; ++t)
      #pragma unroll
      for (int r = 0; r < 4; ++r) {
        const float e = __expf(accS[t][r] - mx);
        accS[t][r] = e; sum += e;
      }
    sum += __shfl_xor(sum, 16);
    sum += __shfl_xor(sum, 32);
    const float rcp = 1.f / sum;
    #pragma unroll
    for (int t = 0; t < 8; ++t) {
      const int j0 = t * 16 + lg * 4;
      const int chunk = j0 >> 3;
      const int csw = (chunk & ~7) | ((chunk & 7) ^ (p & 7));
      st4(E + p * 192 + csw * 8 + (j0 & 7),
          f2b(accS[t][0] * rcp), f2b(accS[t][1] * rcp),
          f2b(accS[t][2] * rcp), f2b(accS[t][3] * rcp));
    }
    float mx2 = -3.0e38f;
    #pragma unroll
    for (int t = 0; t < 4; ++t)
      #pragma unroll
      for (int r = 0; r < 4; ++r) mx2 = fmaxf(mx2, accA[t][r]);
    mx2 = fmaxf(mx2, __shfl_xor(mx2, 16));
    mx2 = fmaxf(mx2, __shfl_xor(mx2, 32));
    float sum2 = 0.f;
    #pragma unroll
    for (int t = 0; t < 4; ++t)
      #pragma unroll
      for (int r = 0; r < 4; ++r) {
        const float e = __expf(accA[t][r] - mx2);
        accA[t][r] = e; sum2 += e;
      }
    sum2 += __shfl_xor(sum2, 16);
    sum2 += __shfl_xor(sum2, 32);
    const float rcp2 = 1.f / sum2;
    #pragma unroll
    for (int t = 0; t < 4; ++t) {
      const int j0 = 128 + t * 16 + lg * 4;
      const int chunk = j0 >> 3;
      const int csw = (chunk & ~7) | ((chunk & 7) ^ (p & 7));
      st4(E + p * 192 + csw * 8 + (j0 & 7),
          f2b(accA[t][0] * rcp2), f2b(accA[t][1] * rcp2),
          f2b(accA[t][2] * rcp2), f2b(accA[t][3] * rcp2));
    }
  }

  // ================= OUT PHASE: y = Wy @ E =================
  f4 acc8[16];
  #pragma unroll
  for (int t = 0; t < 16; ++t) acc8[t] = zero4;
  bf8 wReg[4];
  #pragma unroll
  for (int j = 0; j < 4; ++j) wReg[j] = *(const bf8*)(wSrc[j]);
  #pragma unroll
  for (int j = 0; j < 4; ++j) *(bf8*)(LDS + 12288 + wLds[j]) = wReg[j];
  __syncthreads();   // E + Wybuf0 visible

  for (int q = 0; q < 6; ++q) {
    const int buf = q & 1;
    if (q < 5) {
      #pragma unroll
      for (int j = 0; j < 4; ++j) wReg[j] = *(const bf8*)(wSrc[j] + (q + 1) * 32);
    }
    const int jchunk = q * 4 + lg;
    const int csw = (jchunk & ~7) | ((jchunk & 7) ^ (p & 7));
    const bf8 ef = *(const bf8*)(E + p * 192 + csw * 8);
    const u16* Wb = LDS + 12288 + buf * 8192;
    #pragma unroll
    for (int t = 0; t < 16; ++t) {
      const int row = t * 16 + l15;
      const int sw = 8 * (lg ^ ((row >> 1) & 3));
      const bf8 wf = *(const bf8*)(Wb + row * 32 + sw);
      acc8[t] = MFMA(wf, ef, acc8[t]);
    }
    if (q < 5) {
      u16* Wn_ = LDS + 12288 + (buf ^ 1) * 8192;
      #pragma unroll
      for (int j = 0; j < 4; ++j) *(bf8*)(Wn_ + wLds[j]) = wReg[j];
    }
    __syncthreads();
  }

  // ================= EPILOGUE: BN + residual + leaky =================
  const size_t pcol = (size_t)p0g + p;
  #pragma unroll
  for (int t = 0; t < 16; ++t) {
    #pragma unroll
    for (int r = 0; r < 4; ++r) {
      const int c = t * 16 + lg * 4 + r;
      const size_t o = (((size_t)b * 256 + c) << 13) + pcol;
      const float z = x[o] + acc8[t][r] * scL[c] + biL[c];
      out[o] = z > 0.f ? z : 0.2f * z;
    }
  }
}

// ---------------------------------------------------------------------------
extern "C" void kernel_launch(void* const* d_in, const int* in_sizes, int n_in,
                              void* d_out, int out_size, void* d_ws, size_t ws_size,
                              hipStream_t stream) {
  const float* x      = (const float*)d_in[0];
  const float* curves = (const float*)d_in[1];
  const float* w_att  = (const float*)d_in[2];
  const float* wa     = (const float*)d_in[3];
  const float* wb     = (const float*)d_in[4];
  const float* wc     = (const float*)d_in[5];
  const float* wn     = (const float*)d_in[6];
  const float* wl     = (const float*)d_in[7];
  const float* wd     = (const float*)d_in[8];
  const float* bng    = (const float*)d_in[9];
  const float* bnb    = (const float*)d_in[10];
  const float* bnm    = (const float*)d_in[11];
  const float* bnv    = (const float*)d_in[12];
  float* out = (float*)d_out;
  float* ws  = (float*)d_ws;

  float* att    = ws;
  float* smi    = ws + 131072;
  float* sma    = ws + 262144;
  float* cinter = ws + 393216;
  float* cintra = ws + 917504;
  float* amat   = ws + 1179648;
  float* bmat   = ws + 1441792;
  float* anmat  = ws + 1572864;
  float* blmat  = ws + 1835008;

  u16* wsb = (u16*)d_ws;
  u16* AnH = wsb;                     // [b][128][256]
  u16* AnL = wsb + 524288;
  u16* BlH = wsb + 1048576;           // [b][64][256]
  u16* BlL = wsb + 1310720;
  u16* Wyp = wsb + 1572864;           // [b][256][192]

  k_att    <<<dim3(B_ * 8),   dim3(256), 0, stream>>>(curves, w_att, att);
  k_softmax<<<dim3(B_),       dim3(256), 0, stream>>>(att, smi, sma);
  k_agg    <<<dim3(B_ * C_),  dim3(256), 0, stream>>>(curves, smi, sma, cinter, cintra);
  k_ab     <<<dim3(B_ * 8),   dim3(256), 0, stream>>>(wa, wb, cinter, cintra, amat, bmat);
  k_nl     <<<dim3(B_ * 8),   dim3(256), 0, stream>>>(wn, wl, amat, bmat, anmat, blmat);
  k_fold   <<<dim3(B_ * 24),  dim3(256), 0, stream>>>(wc, wd, amat, bmat, anmat, blmat,
                                                      AnH, AnL, BlH, BlL, Wyp);
  k_big    <<<dim3(2048),     dim3(256), 0, stream>>>(x, AnH, AnL, BlH, BlL, Wyp,
                                                      bng, bnb, bnm, bnv, out);
}